// Round 18
// baseline (92.932 us; speedup 1.0000x reference)
//
#include <hip/hip_runtime.h>
#include <cstdint>
#include <cstddef>

typedef _Float16 half8 __attribute__((ext_vector_type(8)));
typedef _Float16 half4v __attribute__((ext_vector_type(4)));
typedef float f32x4 __attribute__((ext_vector_type(4)));
typedef int int4v __attribute__((ext_vector_type(4)));

#define EMBD 1024
#define NHEAD 16
#define TSEQ 2048
#define NB 2
#define HD 64
#define NBH (NB*NHEAD)          // 32
#define SCK 0.18033688f         // 0.125 * log2(e)

static __device__ __forceinline__ void gload_lds16(const void* g, void* l) {
    __builtin_amdgcn_global_load_lds((const __attribute__((address_space(1))) void*)g,
                                     (__attribute__((address_space(3))) void*)l,
                                     16, 0, 0);
}

static __device__ __forceinline__ int pk2(float a, float b) {
    return __builtin_bit_cast(int, __builtin_amdgcn_cvt_pkrtz(a, b));
}

// ---------------- fused prep: x fp32->fp16 convert + both W transposes ----------------
__global__ __launch_bounds__(256) void k_prep(
    const float* __restrict__ x,  _Float16* __restrict__ xh,
    const float* __restrict__ Wa, const float* __restrict__ Wp,
    _Float16* __restrict__ WaT,   _Float16* __restrict__ WpT)
{
    const int bx = blockIdx.x;
    if (bx < 4096) {
        int i = bx * 256 + threadIdx.x;
        float4 v = ((const float4*)x)[i];
        half4v h;
        h.x = (_Float16)v.x; h.y = (_Float16)v.y; h.z = (_Float16)v.z; h.w = (_Float16)v.w;
        ((half4v*)xh)[i] = h;
        return;
    }
    __shared__ float tile[32][33];
    const int idx = bx - 4096;          // 0..4095
    const int bxx = idx & 127;          // 0..127 (96 Wa + 32 Wp)
    const int byy = idx >> 7;           // 0..31
    const bool isA = bxx < 96;
    const float* in  = isA ? Wa : Wp;
    _Float16* out    = isA ? WaT : WpT;
    const int C      = isA ? 3072 : 1024;
    const int c0 = (isA ? bxx : bxx - 96) * 32, r0 = byy * 32;
    const int tx = threadIdx.x & 31, ty = threadIdx.x >> 5;   // 32 x 8
    #pragma unroll
    for (int j = 0; j < 4; ++j)
        tile[ty + 8*j][tx] = in[(size_t)(r0 + ty + 8*j) * C + c0 + tx];
    __syncthreads();
    #pragma unroll
    for (int j = 0; j < 4; ++j)
        out[(size_t)(c0 + ty + 8*j) * 1024 + r0 + tx] = (_Float16)tile[tx][ty + 8*j];
}

// ---------------- merged QKV GEMM: 128m x (64n x 3), 512 threads / 8 waves ----------------
__global__ __launch_bounds__(512, 4) void k_gemm_qkv(
    const _Float16* __restrict__ A,     // [4096][1024]
    const _Float16* __restrict__ Bt,    // [3072][1024]
    const float* __restrict__ bias,     // [3072]
    _Float16* __restrict__ outq,        // [4096][3072] (V region unused)
    _Float16* __restrict__ VT)          // [32][64][2048]
{
    __shared__ _Float16 smem[20480];    // As[0:8192) 128x64 ; Bs[q]=8192+q*4096 (64x64)
    _Float16* As = smem;

    const int d   = blockIdx.x;                 // 0..511
    const int xcd = d & 7;
    const int idx = d >> 3;                     // 0..63
    const int mt  = (xcd >> 1) * 8 + (idx & 7);   // 0..31
    const int ntl = (xcd &  1) * 8 + (idx >> 3);  // 0..15 (head)
    const int m0 = mt * 128;
    const int hc = ntl * 64;                    // head column base

    const int tid  = threadIdx.x;
    const int lane = tid & 63;
    const int w    = tid >> 6;                  // 0..7
    const int wm   = w >> 2;                    // 0..1 (64m block)
    const int wn   = w & 3;                     // 0..3 (48n block)
    const int l15  = lane & 15;
    const int lg   = lane >> 4;

    f32x4 acc[4][3];
    #pragma unroll
    for (int i = 0; i < 4; ++i)
        #pragma unroll
        for (int j = 0; j < 3; ++j)
            acc[i][j] = (f32x4){0.f, 0.f, 0.f, 0.f};

    for (int kt = 0; kt < 16; ++kt) {
        __syncthreads();
        #pragma unroll
        for (int c = 0; c < 2; ++c) {          // A: 1024 segs, 2/thread
            int s = c * 512 + tid;
            int r = s >> 3, sl = s & 7;
            const _Float16* ga = A + (size_t)(m0 + r) * 1024 + kt * 64 + ((sl ^ (r & 7)) * 8);
            gload_lds16(ga, (char*)As + s * 16);
        }
        {                                      // B: 3 x 512 segs, 3/thread
            int s = tid;
            int r = s >> 3, sl = s & 7;
            size_t goff = (size_t)(hc + r) * 1024 + kt * 64 + ((sl ^ (r & 7)) * 8);
            #pragma unroll
            for (int q = 0; q < 3; ++q)
                gload_lds16(Bt + goff + (size_t)q * 1024 * 1024,
                            (char*)(smem + 8192 + q * 4096) + s * 16);
        }
        __syncthreads();

        half8 af[4][2];
        #pragma unroll
        for (int mf = 0; mf < 4; ++mf) {
            int r = wm * 64 + mf * 16 + l15;
            #pragma unroll
            for (int ks = 0; ks < 2; ++ks)
                af[mf][ks] = *(const half8*)((const char*)As + r * 128 + (((ks * 4 + lg) ^ (r & 7)) * 16));
        }
        half8 bf[3][2];
        #pragma unroll
        for (int nf = 0; nf < 3; ++nf) {
            int nn = wn * 48 + nf * 16;        // 0..176, wave-uniform region
            const char* BsQ = (const char*)(smem + 8192 + (nn >> 6) * 4096);
            int r = (nn & 63) + l15;
            #pragma unroll
            for (int ks = 0; ks < 2; ++ks)
                bf[nf][ks] = *(const half8*)(BsQ + r * 128 + (((ks * 4 + lg) ^ (r & 7)) * 16));
        }
        #pragma unroll
        for (int mf = 0; mf < 4; ++mf)
            #pragma unroll
            for (int nf = 0; nf < 3; ++nf) {
                acc[mf][nf] = __builtin_amdgcn_mfma_f32_16x16x32_f16(af[mf][0], bf[nf][0], acc[mf][nf], 0, 0, 0);
                acc[mf][nf] = __builtin_amdgcn_mfma_f32_16x16x32_f16(af[mf][1], bf[nf][1], acc[mf][nf], 0, 0, 0);
            }
    }

    // ---- epilogues ----
    #pragma unroll
    for (int nf = 0; nf < 3; ++nf) {
        int nn = wn * 48 + nf * 16;
        int q  = nn >> 6;                      // wave-uniform
        if (q < 2) {
            int col = (nn & 63) + l15;
            float bv = bias[q * 1024 + hc + col];
            float osc = (q == 1) ? SCK : 1.0f;
            #pragma unroll
            for (int mf = 0; mf < 4; ++mf) {
                #pragma unroll
                for (int j = 0; j < 4; ++j) {
                    int m = m0 + wm * 64 + mf * 16 + lg * 4 + j;
                    outq[(size_t)m * 3072 + q * 1024 + hc + col] = (_Float16)((acc[mf][nf][j] + bv) * osc);
                }
            }
        }
    }
    __syncthreads();                           // all fragment reads of smem done
    #pragma unroll
    for (int nf = 0; nf < 3; ++nf) {
        int nn = wn * 48 + nf * 16;
        if ((nn >> 6) == 2) {
            int col = (nn & 63) + l15;
            float bv = bias[2048 + hc + col];
            #pragma unroll
            for (int mf = 0; mf < 4; ++mf) {
                #pragma unroll
                for (int j = 0; j < 4; ++j) {
                    int ml = wm * 64 + mf * 16 + lg * 4 + j;   // t_local
                    smem[ml * 65 + col] = (_Float16)(acc[mf][nf][j] + bv);
                }
            }
        }
    }
    __syncthreads();

    {
        const int b     = m0 >> 11;
        const int tloc0 = m0 & 2047;
        _Float16* vbase = VT + ((size_t)(b * 16 + ntl) * 64) * 2048 + tloc0;
        #pragma unroll
        for (int c = 0; c < 2; ++c) {
            int seg = c * 512 + tid;           // 0..1023
            int dd  = seg >> 4;                // 0..63
            int s   = seg & 15;                // 16B segment
            half8 hv8;
            #pragma unroll
            for (int e = 0; e < 8; ++e) {
                int p = s * 8 + e;
                int k = 16 * (2 * (p >> 5) + ((p & 7) >> 2)) + 4 * ((p >> 3) & 3) + (p & 3);
                hv8[e] = smem[k * 65 + dd];
            }
            *(half8*)&vbase[(size_t)dd * 2048 + s * 8] = hv8;
        }
    }
}

// ---------------- proj GEMM: 64x128 tile, 2D XCD chunks ----------------
__global__ __launch_bounds__(256) void k_gemm_proj(
    const _Float16* __restrict__ A,     // [4096][1024] (Y)
    const _Float16* __restrict__ Bt,    // [1024][1024] (WpT)
    const float* __restrict__ bias,     // [1024]
    float* __restrict__ outf)           // [4096][1024]
{
    __shared__ _Float16 As[64 * 64];    // 8 KB
    __shared__ _Float16 Bs[128 * 64];   // 16 KB

    const int d   = blockIdx.x;                 // 0..511
    const int xcd = d & 7;
    const int idx = d >> 3;                     // 0..63
    const int mt  = (xcd >> 1) * 16 + (idx & 15);
    const int nt  = (xcd &  1) * 4  + (idx >> 4);
    const int m0 = mt * 64, n0 = nt * 128;

    const int tid  = threadIdx.x;
    const int lane = tid & 63;
    const int wn   = tid >> 6;                  // wave 0..3 = n-slice
    const int l15  = lane & 15;
    const int lg   = lane >> 4;

    f32x4 acc[4][2];
    #pragma unroll
    for (int i = 0; i < 4; ++i) {
        acc[i][0] = (f32x4){0.f, 0.f, 0.f, 0.f};
        acc[i][1] = (f32x4){0.f, 0.f, 0.f, 0.f};
    }

    for (int kt = 0; kt < 16; ++kt) {
        __syncthreads();
        #pragma unroll
        for (int c = 0; c < 2; ++c) {
            int s = c * 256 + tid;
            int r = s >> 3, sl = s & 7;
            const _Float16* ga = A + (size_t)(m0 + r) * 1024 + kt * 64 + ((sl ^ (r & 7)) * 8);
            gload_lds16(ga, (char*)As + s * 16);
        }
        #pragma unroll
        for (int c = 0; c < 4; ++c) {
            int s = c * 256 + tid;
            int r = s >> 3, sl = s & 7;
            const _Float16* gb = Bt + (size_t)(n0 + r) * 1024 + kt * 64 + ((sl ^ (r & 7)) * 8);
            gload_lds16(gb, (char*)Bs + s * 16);
        }
        __syncthreads();

        half8 af[4][2], bf[2][2];
        #pragma unroll
        for (int mf = 0; mf < 4; ++mf) {
            int r = mf * 16 + l15;
            #pragma unroll
            for (int ks = 0; ks < 2; ++ks)
                af[mf][ks] = *(const half8*)((const char*)As + r * 128 + (((ks * 4 + lg) ^ (r & 7)) * 16));
        }
        #pragma unroll
        for (int nf = 0; nf < 2; ++nf) {
            int r = wn * 32 + nf * 16 + l15;
            #pragma unroll
            for (int ks = 0; ks < 2; ++ks)
                bf[nf][ks] = *(const half8*)((const char*)Bs + r * 128 + (((ks * 4 + lg) ^ (r & 7)) * 16));
        }
        #pragma unroll
        for (int mf = 0; mf < 4; ++mf)
            #pragma unroll
            for (int nf = 0; nf < 2; ++nf) {
                acc[mf][nf] = __builtin_amdgcn_mfma_f32_16x16x32_f16(af[mf][0], bf[nf][0], acc[mf][nf], 0, 0, 0);
                acc[mf][nf] = __builtin_amdgcn_mfma_f32_16x16x32_f16(af[mf][1], bf[nf][1], acc[mf][nf], 0, 0, 0);
            }
    }

    float bv[2];
    bv[0] = bias[n0 + wn * 32 + l15];
    bv[1] = bias[n0 + wn * 32 + 16 + l15];

    #pragma unroll
    for (int mf = 0; mf < 4; ++mf) {
        #pragma unroll
        for (int j = 0; j < 4; ++j) {
            int m = m0 + mf * 16 + lg * 4 + j;
            float* po = outf + (size_t)m * 1024 + n0 + wn * 32 + l15;
            po[0]  = acc[mf][0][j] + bv[0];
            po[16] = acc[mf][1][j] + bv[1];
        }
    }
}

// ---------------- causal flash attention: 4 waves x 32 q-rows, guard-free ----------------
// Each K/V LDS fragment read feeds TWO MFMAs (q-frag0 rows w*16+l15, frag1 +64).
// No skip logic: all 8 k-fragments computed for both frags; causal handled purely by
// the ternary mask on the diagonal tile. Named scalar staging regs (R13 pattern).
__global__ __launch_bounds__(256, 2) void k_attn(
    const _Float16* __restrict__ qkv,   // natural (Q cols 0..1023, K cols 1024..2047 pre-scaled)
    const _Float16* __restrict__ VTg,   // [bh][d][2048] kappa-permuted
    _Float16* __restrict__ Y)
{
    __shared__ _Float16 Kt[2][8192];    // [k][d], 16B slots XOR (k&7)
    __shared__ _Float16 Vt[2][8192];    // [d][p], 16B slots XOR (d&15)

    const int tid  = threadIdx.x;
    const int lane = tid & 63;
    const int w    = tid >> 6;           // 0..3
    const int l15  = lane & 15;
    const int lg   = lane >> 4;
    const int bh   = blockIdx.x;
    const int by   = blockIdx.y;
    const int qt   = (by < 8) ? (15 - by) : (by - 8);   // pairs sum to 17 tiles
    const int b    = bh >> 4, h = bh & 15;

    // staging segments (named, explicit): seg = tid, 256+tid, 512+tid, 768+tid
    const int sg0 = tid, sg1 = 256 + tid, sg2 = 512 + tid, sg3 = 768 + tid;
    const size_t k0 = (size_t)(sg0 >> 3) * 3072 + (((sg0 & 7) ^ ((sg0 >> 3) & 7)) * 8);
    const size_t k1 = (size_t)(sg1 >> 3) * 3072 + (((sg1 & 7) ^ ((sg1 >> 3) & 7)) * 8);
    const size_t k2 = (size_t)(sg2 >> 3) * 3072 + (((sg2 & 7) ^ ((sg2 >> 3) & 7)) * 8);
    const size_t k3 = (size_t)(sg3 >> 3) * 3072 + (((sg3 & 7) ^ ((sg3 >> 3) & 7)) * 8);
    const size_t v0 = (size_t)(sg0 >> 4) * 2048 + (((sg0 & 15) ^ ((sg0 >> 4) & 15)) * 8);
    const size_t v1 = (size_t)(sg1 >> 4) * 2048 + (((sg1 & 15) ^ ((sg1 >> 4) & 15)) * 8);
    const size_t v2 = (size_t)(sg2 >> 4) * 2048 + (((sg2 & 15) ^ ((sg2 >> 4) & 15)) * 8);
    const size_t v3 = (size_t)(sg3 >> 4) * 2048 + (((sg3 & 15) ^ ((sg3 >> 4) & 15)) * 8);
    const _Float16* kBase = qkv + (size_t)(b * 2048) * 3072 + 1024 + h * 64;
    const _Float16* vBase = VTg + (size_t)bh * TSEQ * HD;

    const int x7   = l15 & 7;
    const int kph0 = (lg ^ x7) * 8;
    const int kph1 = ((4 + lg) ^ x7) * 8;

    const int qr0 = qt * 128 + w * 16 + l15;
    const _Float16* qp0 = qkv + (size_t)(b * 2048 + qr0) * 3072 + h * 64;
    const _Float16* qp1 = qp0 + (size_t)64 * 3072;
    half8 qa0 = *(const half8*)&qp0[lg * 8];
    half8 qa1 = *(const half8*)&qp0[32 + lg * 8];
    half8 qa2 = *(const half8*)&qp1[lg * 8];
    half8 qa3 = *(const half8*)&qp1[32 + lg * 8];

    half8 ones;
    #pragma unroll
    for (int i = 0; i < 8; ++i) ones[i] = (_Float16)1.0f;

    f32x4 yac0[4], yac1[4];
    #pragma unroll
    for (int nf = 0; nf < 4; ++nf) {
        yac0[nf] = (f32x4){0.f, 0.f, 0.f, 0.f};
        yac1[nf] = (f32x4){0.f, 0.f, 0.f, 0.f};
    }
    f32x4 lsum0 = (f32x4){0.f, 0.f, 0.f, 0.f};
    f32x4 lsum1 = (f32x4){0.f, 0.f, 0.f, 0.f};

    const int nkt = qt + 1;
    const int qg0 = qt * 128 + w * 16 + l15;        // causal bound frag0
    const int qg1 = qg0 + 64;                       // frag1

    // prologue: tile 0 into named regs
    half8 kra0 = *(const half8*)(kBase + k0);
    half8 kra1 = *(const half8*)(kBase + k1);
    half8 kra2 = *(const half8*)(kBase + k2);
    half8 kra3 = *(const half8*)(kBase + k3);
    half8 vra0 = *(const half8*)(vBase + v0);
    half8 vra1 = *(const half8*)(vBase + v1);
    half8 vra2 = *(const half8*)(vBase + v2);
    half8 vra3 = *(const half8*)(vBase + v3);

    for (int kt = 0; kt < nkt; ++kt) {
        const int cur = kt & 1;
        _Float16* KtC = Kt[cur];
        _Float16* VtC = Vt[cur];
        *(half8*)&KtC[sg0 * 8] = kra0;
        *(half8*)&KtC[sg1 * 8] = kra1;
        *(half8*)&KtC[sg2 * 8] = kra2;
        *(half8*)&KtC[sg3 * 8] = kra3;
        *(half8*)&VtC[sg0 * 8] = vra0;
        *(half8*)&VtC[sg1 * 8] = vra1;
        *(half8*)&VtC[sg2 * 8] = vra2;
        *(half8*)&VtC[sg3 * 8] = vra3;
        if (kt + 1 < nkt) {                    // next-tile loads stay in flight across barrier
            const _Float16* kp = kBase + (size_t)(kt + 1) * 128 * 3072;
            const _Float16* vp = vBase + (size_t)(kt + 1) * 128;
            kra0 = *(const half8*)(kp + k0);
            kra1 = *(const half8*)(kp + k1);
            kra2 = *(const half8*)(kp + k2);
            kra3 = *(const half8*)(kp + k3);
            vra0 = *(const half8*)(vp + v0);
            vra1 = *(const half8*)(vp + v1);
            vra2 = *(const half8*)(vp + v2);
            vra3 = *(const half8*)(vp + v3);
        }
        asm volatile("s_waitcnt lgkmcnt(0)" ::: "memory");   // ds_writes visible; vmcnt NOT drained
        __builtin_amdgcn_s_barrier();
        __builtin_amdgcn_sched_barrier(0);

        const bool diag = (kt == nkt - 1);
        const int kb0g  = kt * 128;

        // S = K Q^T for both q-frags; each kb read feeds 2 MFMAs
        f32x4 s0[8], s1[8];
        __builtin_amdgcn_s_setprio(1);
        #pragma unroll
        for (int f = 0; f < 8; ++f) {
            int rr = f * 16 + l15;
            half8 kb0 = *(const half8*)&KtC[rr * 64 + kph0];
            half8 kb1 = *(const half8*)&KtC[rr * 64 + kph1];
            f32x4 z0 = (f32x4){0.f, 0.f, 0.f, 0.f};
            f32x4 z1 = (f32x4){0.f, 0.f, 0.f, 0.f};
            z0 = __builtin_amdgcn_mfma_f32_16x16x32_f16(kb0, qa0, z0, 0, 0, 0);
            z0 = __builtin_amdgcn_mfma_f32_16x16x32_f16(kb1, qa1, z0, 0, 0, 0);
            z1 = __builtin_amdgcn_mfma_f32_16x16x32_f16(kb0, qa2, z1, 0, 0, 0);
            z1 = __builtin_amdgcn_mfma_f32_16x16x32_f16(kb1, qa3, z1, 0, 0, 0);
            s0[f] = z0;
            s1[f] = z1;
        }
        __builtin_amdgcn_s_setprio(0);

        // P = exp2(S); masked (diagonal tile) -> exact 0
        if (diag) {
            #pragma unroll
            for (int f = 0; f < 8; ++f)
                #pragma unroll
                for (int j = 0; j < 4; ++j) {
                    int kk = kb0g + 16 * f + 4 * lg + j;
                    s0[f][j] = (kk > qg0) ? 0.f : exp2f(s0[f][j]);
                    s1[f][j] = (kk > qg1) ? 0.f : exp2f(s1[f][j]);
                }
        } else {
            #pragma unroll
            for (int f = 0; f < 8; ++f)
                #pragma unroll
                for (int j = 0; j < 4; ++j) {
                    s0[f][j] = exp2f(s0[f][j]);
                    s1[f][j] = exp2f(s1[f][j]);
                }
        }

        // PV: each vb read feeds 2 MFMAs
        __builtin_amdgcn_s_setprio(1);
        #pragma unroll
        for (int t = 0; t < 4; ++t) {
            int4v pi0, pi1;
            pi0[0] = pk2(s0[2 * t][0],     s0[2 * t][1]);
            pi0[1] = pk2(s0[2 * t][2],     s0[2 * t][3]);
            pi0[2] = pk2(s0[2 * t + 1][0], s0[2 * t + 1][1]);
            pi0[3] = pk2(s0[2 * t + 1][2], s0[2 * t + 1][3]);
            pi1[0] = pk2(s1[2 * t][0],     s1[2 * t][1]);
            pi1[1] = pk2(s1[2 * t][2],     s1[2 * t][3]);
            pi1[2] = pk2(s1[2 * t + 1][0], s1[2 * t + 1][1]);
            pi1[3] = pk2(s1[2 * t + 1][2], s1[2 * t + 1][3]);
            half8 pa0 = __builtin_bit_cast(half8, pi0);
            half8 pa1 = __builtin_bit_cast(half8, pi1);
            lsum0 = __builtin_amdgcn_mfma_f32_16x16x32_f16(pa0, ones, lsum0, 0, 0, 0);
            lsum1 = __builtin_amdgcn_mfma_f32_16x16x32_f16(pa1, ones, lsum1, 0, 0, 0);
            #pragma unroll
            for (int nf = 0; nf < 4; ++nf) {
                half8 vb = *(const half8*)&VtC[(nf * 16 + l15) * 128 + (((t * 4 + lg) ^ l15) * 8)];
                yac0[nf] = __builtin_amdgcn_mfma_f32_16x16x32_f16(pa0, vb, yac0[nf], 0, 0, 0);
                yac1[nf] = __builtin_amdgcn_mfma_f32_16x16x32_f16(pa1, vb, yac1[nf], 0, 0, 0);
            }
        }
        __builtin_amdgcn_s_setprio(0);
    }

    // normalize + store both q-frags (token-major)
    const int trow = qt * 128 + w * 16 + lg * 4;
    #pragma unroll
    for (int j = 0; j < 4; ++j) {
        float inv0 = 1.f / lsum0[j];
        float inv1 = 1.f / lsum1[j];
        #pragma unroll
        for (int nf = 0; nf < 4; ++nf) {
            Y[((size_t)b * TSEQ + trow + j) * EMBD + h * 64 + nf * 16 + l15]
                = (_Float16)(yac0[nf][j] * inv0);
            Y[((size_t)b * TSEQ + trow + 64 + j) * EMBD + h * 64 + nf * 16 + l15]
                = (_Float16)(yac1[nf][j] * inv1);
        }
    }
}

// ---------------- launch ----------------
extern "C" void kernel_launch(void* const* d_in, const int* in_sizes, int n_in,
                              void* d_out, int out_size, void* d_ws, size_t ws_size,
                              hipStream_t stream) {
    const float* x  = (const float*)d_in[0];
    const float* Wa = (const float*)d_in[1];
    const float* ba = (const float*)d_in[2];
    const float* Wp = (const float*)d_in[3];
    const float* bp = (const float*)d_in[4];
    float* out = (float*)d_out;

    _Float16* Xh   = (_Float16*)d_ws;                  // 4096x1024 (aliased by Yh later)
    _Float16* WaT  = Xh   + (size_t)4096 * 1024;       // 3072x1024
    _Float16* WpT  = WaT  + (size_t)3072 * 1024;       // 1024x1024
    _Float16* QKVn = WpT  + (size_t)1024 * 1024;       // 4096x3072 (V region unused)
    _Float16* VTb  = QKVn + (size_t)4096 * 3072;       // 32x64x2048 kappa-permuted
    _Float16* Yh   = Xh;                               // alias: Xh dead after GEMM1

    k_prep<<<8192, 256, 0, stream>>>(x, Xh, Wa, Wp, WaT, WpT);

    k_gemm_qkv<<<512, 512, 0, stream>>>(Xh, WaT, ba, QKVn, VTb);

    k_attn<<<dim3(NBH, 16), 256, 0, stream>>>(QKVn, VTb, Yh);

    k_gemm_proj<<<512, 256, 0, stream>>>(Yh, WpT, bp, out);
}

// Round 19
// 90.928 us; speedup vs baseline: 1.0220x; 1.0220x over previous
//
#include <hip/hip_runtime.h>
#include <cstdint>
#include <cstddef>

typedef _Float16 half8 __attribute__((ext_vector_type(8)));
typedef _Float16 half4v __attribute__((ext_vector_type(4)));
typedef float f32x4 __attribute__((ext_vector_type(4)));
typedef int int4v __attribute__((ext_vector_type(4)));

#define EMBD 1024
#define NHEAD 16
#define TSEQ 2048
#define NB 2
#define HD 64
#define NBH (NB*NHEAD)          // 32
#define SCK 0.18033688f         // 0.125 * log2(e)

static __device__ __forceinline__ void gload_lds16(const void* g, void* l) {
    __builtin_amdgcn_global_load_lds((const __attribute__((address_space(1))) void*)g,
                                     (__attribute__((address_space(3))) void*)l,
                                     16, 0, 0);
}

static __device__ __forceinline__ int pk2(float a, float b) {
    return __builtin_bit_cast(int, __builtin_amdgcn_cvt_pkrtz(a, b));
}

// ---------------- fused prep: x fp32->fp16 convert (2 float4/thread) + W transposes ----------------
__global__ __launch_bounds__(256) void k_prep(
    const float* __restrict__ x,  _Float16* __restrict__ xh,
    const float* __restrict__ Wa, const float* __restrict__ Wp,
    _Float16* __restrict__ WaT,   _Float16* __restrict__ WpT)
{
    const int bx = blockIdx.x;
    if (bx < 2048) {
        #pragma unroll
        for (int c = 0; c < 2; ++c) {
            int i = bx * 512 + c * 256 + threadIdx.x;
            float4 v = ((const float4*)x)[i];
            half4v h;
            h.x = (_Float16)v.x; h.y = (_Float16)v.y; h.z = (_Float16)v.z; h.w = (_Float16)v.w;
            ((half4v*)xh)[i] = h;
        }
        return;
    }
    __shared__ float tile[32][33];
    const int idx = bx - 2048;          // 0..4095
    const int bxx = idx & 127;          // 0..127 (96 Wa + 32 Wp)
    const int byy = idx >> 7;           // 0..31
    const bool isA = bxx < 96;
    const float* in  = isA ? Wa : Wp;
    _Float16* out    = isA ? WaT : WpT;
    const int C      = isA ? 3072 : 1024;
    const int c0 = (isA ? bxx : bxx - 96) * 32, r0 = byy * 32;
    const int tx = threadIdx.x & 31, ty = threadIdx.x >> 5;   // 32 x 8
    #pragma unroll
    for (int j = 0; j < 4; ++j)
        tile[ty + 8*j][tx] = in[(size_t)(r0 + ty + 8*j) * C + c0 + tx];
    __syncthreads();
    #pragma unroll
    for (int j = 0; j < 4; ++j)
        out[(size_t)(c0 + ty + 8*j) * 1024 + r0 + tx] = (_Float16)tile[tx][ty + 8*j];
}

// ---------------- merged QKV GEMM: 128m x (64n x 3), 512 threads / 8 waves ----------------
__global__ __launch_bounds__(512, 4) void k_gemm_qkv(
    const _Float16* __restrict__ A,     // [4096][1024]
    const _Float16* __restrict__ Bt,    // [3072][1024]
    const float* __restrict__ bias,     // [3072]
    _Float16* __restrict__ outq,        // [4096][3072] (V region unused)
    _Float16* __restrict__ VT)          // [32][64][2048]
{
    __shared__ _Float16 smem[20480];    // As[0:8192) 128x64 ; Bs[q]=8192+q*4096 (64x64)
    _Float16* As = smem;

    const int d   = blockIdx.x;                 // 0..511
    const int xcd = d & 7;
    const int idx = d >> 3;                     // 0..63
    const int mt  = (xcd >> 1) * 8 + (idx & 7);   // 0..31
    const int ntl = (xcd &  1) * 8 + (idx >> 3);  // 0..15 (head)
    const int m0 = mt * 128;
    const int hc = ntl * 64;                    // head column base

    const int tid  = threadIdx.x;
    const int lane = tid & 63;
    const int w    = tid >> 6;                  // 0..7
    const int wm   = w >> 2;                    // 0..1 (64m block)
    const int wn   = w & 3;                     // 0..3 (48n block)
    const int l15  = lane & 15;
    const int lg   = lane >> 4;

    f32x4 acc[4][3];
    #pragma unroll
    for (int i = 0; i < 4; ++i)
        #pragma unroll
        for (int j = 0; j < 3; ++j)
            acc[i][j] = (f32x4){0.f, 0.f, 0.f, 0.f};

    for (int kt = 0; kt < 16; ++kt) {
        __syncthreads();
        #pragma unroll
        for (int c = 0; c < 2; ++c) {          // A: 1024 segs, 2/thread
            int s = c * 512 + tid;
            int r = s >> 3, sl = s & 7;
            const _Float16* ga = A + (size_t)(m0 + r) * 1024 + kt * 64 + ((sl ^ (r & 7)) * 8);
            gload_lds16(ga, (char*)As + s * 16);
        }
        {                                      // B: 3 x 512 segs, 3/thread
            int s = tid;
            int r = s >> 3, sl = s & 7;
            size_t goff = (size_t)(hc + r) * 1024 + kt * 64 + ((sl ^ (r & 7)) * 8);
            #pragma unroll
            for (int q = 0; q < 3; ++q)
                gload_lds16(Bt + goff + (size_t)q * 1024 * 1024,
                            (char*)(smem + 8192 + q * 4096) + s * 16);
        }
        __syncthreads();

        half8 af[4][2];
        #pragma unroll
        for (int mf = 0; mf < 4; ++mf) {
            int r = wm * 64 + mf * 16 + l15;
            #pragma unroll
            for (int ks = 0; ks < 2; ++ks)
                af[mf][ks] = *(const half8*)((const char*)As + r * 128 + (((ks * 4 + lg) ^ (r & 7)) * 16));
        }
        half8 bf[3][2];
        #pragma unroll
        for (int nf = 0; nf < 3; ++nf) {
            int nn = wn * 48 + nf * 16;        // 0..176, wave-uniform region
            const char* BsQ = (const char*)(smem + 8192 + (nn >> 6) * 4096);
            int r = (nn & 63) + l15;
            #pragma unroll
            for (int ks = 0; ks < 2; ++ks)
                bf[nf][ks] = *(const half8*)(BsQ + r * 128 + (((ks * 4 + lg) ^ (r & 7)) * 16));
        }
        #pragma unroll
        for (int mf = 0; mf < 4; ++mf)
            #pragma unroll
            for (int nf = 0; nf < 3; ++nf) {
                acc[mf][nf] = __builtin_amdgcn_mfma_f32_16x16x32_f16(af[mf][0], bf[nf][0], acc[mf][nf], 0, 0, 0);
                acc[mf][nf] = __builtin_amdgcn_mfma_f32_16x16x32_f16(af[mf][1], bf[nf][1], acc[mf][nf], 0, 0, 0);
            }
    }

    // ---- epilogues ----
    #pragma unroll
    for (int nf = 0; nf < 3; ++nf) {
        int nn = wn * 48 + nf * 16;
        int q  = nn >> 6;                      // wave-uniform
        if (q < 2) {
            int col = (nn & 63) + l15;
            float bv = bias[q * 1024 + hc + col];
            float osc = (q == 1) ? SCK : 1.0f;
            #pragma unroll
            for (int mf = 0; mf < 4; ++mf) {
                #pragma unroll
                for (int j = 0; j < 4; ++j) {
                    int m = m0 + wm * 64 + mf * 16 + lg * 4 + j;
                    outq[(size_t)m * 3072 + q * 1024 + hc + col] = (_Float16)((acc[mf][nf][j] + bv) * osc);
                }
            }
        }
    }
    __syncthreads();                           // all fragment reads of smem done
    #pragma unroll
    for (int nf = 0; nf < 3; ++nf) {
        int nn = wn * 48 + nf * 16;
        if ((nn >> 6) == 2) {
            int col = (nn & 63) + l15;
            float bv = bias[2048 + hc + col];
            #pragma unroll
            for (int mf = 0; mf < 4; ++mf) {
                #pragma unroll
                for (int j = 0; j < 4; ++j) {
                    int ml = wm * 64 + mf * 16 + lg * 4 + j;   // t_local
                    smem[ml * 65 + col] = (_Float16)(acc[mf][nf][j] + bv);
                }
            }
        }
    }
    __syncthreads();

    {
        const int b     = m0 >> 11;
        const int tloc0 = m0 & 2047;
        _Float16* vbase = VT + ((size_t)(b * 16 + ntl) * 64) * 2048 + tloc0;
        #pragma unroll
        for (int c = 0; c < 2; ++c) {
            int seg = c * 512 + tid;           // 0..1023
            int dd  = seg >> 4;                // 0..63
            int s   = seg & 15;                // 16B segment
            half8 hv8;
            #pragma unroll
            for (int e = 0; e < 8; ++e) {
                int p = s * 8 + e;
                int k = 16 * (2 * (p >> 5) + ((p & 7) >> 2)) + 4 * ((p >> 3) & 3) + (p & 3);
                hv8[e] = smem[k * 65 + dd];
            }
            *(half8*)&vbase[(size_t)dd * 2048 + s * 8] = hv8;
        }
    }
}

// ---------------- proj GEMM: 64x128 tile, 2D XCD chunks ----------------
__global__ __launch_bounds__(256) void k_gemm_proj(
    const _Float16* __restrict__ A,     // [4096][1024] (Y)
    const _Float16* __restrict__ Bt,    // [1024][1024] (WpT)
    const float* __restrict__ bias,     // [1024]
    float* __restrict__ outf)           // [4096][1024]
{
    __shared__ _Float16 As[64 * 64];    // 8 KB
    __shared__ _Float16 Bs[128 * 64];   // 16 KB

    const int d   = blockIdx.x;                 // 0..511
    const int xcd = d & 7;
    const int idx = d >> 3;                     // 0..63
    const int mt  = (xcd >> 1) * 16 + (idx & 15);
    const int nt  = (xcd &  1) * 4  + (idx >> 4);
    const int m0 = mt * 64, n0 = nt * 128;

    const int tid  = threadIdx.x;
    const int lane = tid & 63;
    const int wn   = tid >> 6;                  // wave 0..3 = n-slice
    const int l15  = lane & 15;
    const int lg   = lane >> 4;

    f32x4 acc[4][2];
    #pragma unroll
    for (int i = 0; i < 4; ++i) {
        acc[i][0] = (f32x4){0.f, 0.f, 0.f, 0.f};
        acc[i][1] = (f32x4){0.f, 0.f, 0.f, 0.f};
    }

    for (int kt = 0; kt < 16; ++kt) {
        __syncthreads();
        #pragma unroll
        for (int c = 0; c < 2; ++c) {
            int s = c * 256 + tid;
            int r = s >> 3, sl = s & 7;
            const _Float16* ga = A + (size_t)(m0 + r) * 1024 + kt * 64 + ((sl ^ (r & 7)) * 8);
            gload_lds16(ga, (char*)As + s * 16);
        }
        #pragma unroll
        for (int c = 0; c < 4; ++c) {
            int s = c * 256 + tid;
            int r = s >> 3, sl = s & 7;
            const _Float16* gb = Bt + (size_t)(n0 + r) * 1024 + kt * 64 + ((sl ^ (r & 7)) * 8);
            gload_lds16(gb, (char*)Bs + s * 16);
        }
        __syncthreads();

        half8 af[4][2], bf[2][2];
        #pragma unroll
        for (int mf = 0; mf < 4; ++mf) {
            int r = mf * 16 + l15;
            #pragma unroll
            for (int ks = 0; ks < 2; ++ks)
                af[mf][ks] = *(const half8*)((const char*)As + r * 128 + (((ks * 4 + lg) ^ (r & 7)) * 16));
        }
        #pragma unroll
        for (int nf = 0; nf < 2; ++nf) {
            int r = wn * 32 + nf * 16 + l15;
            #pragma unroll
            for (int ks = 0; ks < 2; ++ks)
                bf[nf][ks] = *(const half8*)((const char*)Bs + r * 128 + (((ks * 4 + lg) ^ (r & 7)) * 16));
        }
        #pragma unroll
        for (int mf = 0; mf < 4; ++mf)
            #pragma unroll
            for (int nf = 0; nf < 2; ++nf) {
                acc[mf][nf] = __builtin_amdgcn_mfma_f32_16x16x32_f16(af[mf][0], bf[nf][0], acc[mf][nf], 0, 0, 0);
                acc[mf][nf] = __builtin_amdgcn_mfma_f32_16x16x32_f16(af[mf][1], bf[nf][1], acc[mf][nf], 0, 0, 0);
            }
    }

    float bv[2];
    bv[0] = bias[n0 + wn * 32 + l15];
    bv[1] = bias[n0 + wn * 32 + 16 + l15];

    #pragma unroll
    for (int mf = 0; mf < 4; ++mf) {
        #pragma unroll
        for (int j = 0; j < 4; ++j) {
            int m = m0 + mf * 16 + lg * 4 + j;
            float* po = outf + (size_t)m * 1024 + n0 + wn * 32 + l15;
            po[0]  = acc[mf][0][j] + bv[0];
            po[16] = acc[mf][1][j] + bv[1];
        }
    }
}

// ---------------- causal flash attention (16x16, 8 waves, reg-P, LDS dbuf) ----------------
__global__ __launch_bounds__(512) void k_attn(
    const _Float16* __restrict__ qkv,   // natural (Q cols 0..1023, K cols 1024..2047 pre-scaled)
    const _Float16* __restrict__ VTg,   // [bh][d][2048] kappa-permuted
    _Float16* __restrict__ Y)
{
    __shared__ _Float16 Kt[2][8192];    // [k][d], 16B slots XOR (k&7)
    __shared__ _Float16 Vt[2][8192];    // [d][p], 16B slots XOR (d&15)

    const int tid  = threadIdx.x;
    const int lane = tid & 63;
    const int w    = tid >> 6;           // 0..7 (q-row block)
    const int l15  = lane & 15;
    const int lg   = lane >> 4;
    const int bh   = blockIdx.x;
    const int by   = blockIdx.y;
    const int qt   = (by < 8) ? (15 - by) : (by - 8);   // pairs sum to 17 tiles
    const int b    = bh >> 4, h = bh & 15;

    const int rA  = tid >> 3;
    const int slA = tid & 7;
    const size_t kOffA = (size_t)rA * 3072 + ((slA ^ (rA & 7)) * 8);
    const _Float16* kBase = qkv + (size_t)(b * 2048) * 3072 + 1024 + h * 64;

    const int dA = tid >> 4;
    const int sA = tid & 15;
    const size_t vOffA = (size_t)dA * 2048 + ((sA ^ (dA & 15)) * 8);
    const _Float16* vBase = VTg + (size_t)bh * TSEQ * HD;

    const int x7   = l15 & 7;
    const int kph0 = (lg ^ x7) * 8;
    const int kph1 = ((4 + lg) ^ x7) * 8;

    const int qrow = qt * 128 + w * 16 + l15;
    const _Float16* qptr = qkv + (size_t)(b * 2048 + qrow) * 3072 + h * 64;
    half8 qa0 = *(const half8*)&qptr[lg * 8];
    half8 qa1 = *(const half8*)&qptr[32 + lg * 8];

    half8 ones;
    #pragma unroll
    for (int i = 0; i < 8; ++i) ones[i] = (_Float16)1.0f;

    f32x4 yac[4];
    #pragma unroll
    for (int nf = 0; nf < 4; ++nf) yac[nf] = (f32x4){0.f, 0.f, 0.f, 0.f};
    f32x4 lsum = (f32x4){0.f, 0.f, 0.f, 0.f};

    const int nkt = qt + 1;

    half8 kra = *(const half8*)(kBase + kOffA);
    half8 krb = *(const half8*)(kBase + kOffA + (size_t)64 * 3072);
    half8 vra = *(const half8*)(vBase + vOffA);
    half8 vrb = *(const half8*)(vBase + vOffA + 32 * 2048);

    for (int kt = 0; kt < nkt; ++kt) {
        const int cur = kt & 1;
        _Float16* KtC = Kt[cur];
        _Float16* VtC = Vt[cur];
        *(half8*)&KtC[tid * 8]        = kra;
        *(half8*)&KtC[4096 + tid * 8] = krb;
        *(half8*)&VtC[tid * 8]        = vra;
        *(half8*)&VtC[4096 + tid * 8] = vrb;
        if (kt + 1 < nkt) {                    // next-tile loads stay in flight across barrier
            const _Float16* kp = kBase + (size_t)(kt + 1) * 128 * 3072;
            kra = *(const half8*)(kp + kOffA);
            krb = *(const half8*)(kp + kOffA + (size_t)64 * 3072);
            const _Float16* vp = vBase + (kt + 1) * 128;
            vra = *(const half8*)(vp + vOffA);
            vrb = *(const half8*)(vp + vOffA + 32 * 2048);
        }
        asm volatile("s_waitcnt lgkmcnt(0)" ::: "memory");   // ds_writes visible; vmcnt NOT drained
        __builtin_amdgcn_s_barrier();
        __builtin_amdgcn_sched_barrier(0);

        const bool diag = (kt == nkt - 1);

        f32x4 s[8];
        __builtin_amdgcn_s_setprio(1);
        #pragma unroll
        for (int f = 0; f < 8; ++f) {
            if (diag && f > w) { s[f] = (f32x4){0.f, 0.f, 0.f, 0.f}; continue; }
            int rr = f * 16 + l15;
            half8 kb0 = *(const half8*)&KtC[rr * 64 + kph0];
            half8 kb1 = *(const half8*)&KtC[rr * 64 + kph1];
            f32x4 z = (f32x4){0.f, 0.f, 0.f, 0.f};
            z = __builtin_amdgcn_mfma_f32_16x16x32_f16(kb0, qa0, z, 0, 0, 0);
            z = __builtin_amdgcn_mfma_f32_16x16x32_f16(kb1, qa1, z, 0, 0, 0);
            s[f] = z;
        }
        __builtin_amdgcn_s_setprio(0);

        if (diag) {
            const int qg = qt * 128 + w * 16 + l15;
            #pragma unroll
            for (int f = 0; f < 8; ++f) {
                if (f > w) continue;
                #pragma unroll
                for (int j = 0; j < 4; ++j) {
                    int kk = kt * 128 + 16 * f + 4 * lg + j;
                    s[f][j] = (kk > qg) ? 0.f : exp2f(s[f][j]);
                }
            }
        } else {
            #pragma unroll
            for (int f = 0; f < 8; ++f)
                #pragma unroll
                for (int j = 0; j < 4; ++j) s[f][j] = exp2f(s[f][j]);
        }

        __builtin_amdgcn_s_setprio(1);
        #pragma unroll
        for (int t = 0; t < 4; ++t) {
            int4v pi;
            pi[0] = pk2(s[2 * t][0],     s[2 * t][1]);
            pi[1] = pk2(s[2 * t][2],     s[2 * t][3]);
            pi[2] = pk2(s[2 * t + 1][0], s[2 * t + 1][1]);
            pi[3] = pk2(s[2 * t + 1][2], s[2 * t + 1][3]);
            half8 pa = __builtin_bit_cast(half8, pi);
            lsum = __builtin_amdgcn_mfma_f32_16x16x32_f16(pa, ones, lsum, 0, 0, 0);
            #pragma unroll
            for (int nf = 0; nf < 4; ++nf) {
                half8 vb = *(const half8*)&VtC[(nf * 16 + l15) * 128 + (((t * 4 + lg) ^ l15) * 8)];
                yac[nf] = __builtin_amdgcn_mfma_f32_16x16x32_f16(pa, vb, yac[nf], 0, 0, 0);
            }
        }
        __builtin_amdgcn_s_setprio(0);
    }

    const int trow = qt * 128 + w * 16 + lg * 4;
    #pragma unroll
    for (int j = 0; j < 4; ++j) {
        float inv = 1.f / lsum[j];
        #pragma unroll
        for (int nf = 0; nf < 4; ++nf) {
            float yv = yac[nf][j] * inv;
            Y[((size_t)b * TSEQ + trow + j) * EMBD + h * 64 + nf * 16 + l15] = (_Float16)yv;
        }
    }
}

// ---------------- launch ----------------
extern "C" void kernel_launch(void* const* d_in, const int* in_sizes, int n_in,
                              void* d_out, int out_size, void* d_ws, size_t ws_size,
                              hipStream_t stream) {
    const float* x  = (const float*)d_in[0];
    const float* Wa = (const float*)d_in[1];
    const float* ba = (const float*)d_in[2];
    const float* Wp = (const float*)d_in[3];
    const float* bp = (const float*)d_in[4];
    float* out = (float*)d_out;

    _Float16* Xh   = (_Float16*)d_ws;                  // 4096x1024 (aliased by Yh later)
    _Float16* WaT  = Xh   + (size_t)4096 * 1024;       // 3072x1024
    _Float16* WpT  = WaT  + (size_t)3072 * 1024;       // 1024x1024
    _Float16* QKVn = WpT  + (size_t)1024 * 1024;       // 4096x3072 (V region unused)
    _Float16* VTb  = QKVn + (size_t)4096 * 3072;       // 32x64x2048 kappa-permuted
    _Float16* Yh   = Xh;                               // alias: Xh dead after GEMM1

    k_prep<<<6144, 256, 0, stream>>>(x, Xh, Wa, Wp, WaT, WpT);

    k_gemm_qkv<<<512, 512, 0, stream>>>(Xh, WaT, ba, QKVn, VTb);

    k_attn<<<dim3(NBH, 16), 512, 0, stream>>>(QKVn, VTb, Yh);

    k_gemm_proj<<<512, 256, 0, stream>>>(Yh, WpT, bp, out);
}